// Round 1
// baseline (4333.675 us; speedup 1.0000x reference)
//
#include <hip/hip_runtime.h>

#define Hh 1024
#define NBATCH 128
#define TSTEPS 256
#define DOUT 1024
#define SLOT (NBATCH * Hh)

typedef _Float16 half8 __attribute__((ext_vector_type(8)));
typedef float floatx4 __attribute__((ext_vector_type(4)));

__device__ __forceinline__ float fast_sigmoid(float x) {
  float e = __expf(-x);
  return __builtin_amdgcn_rcpf(1.0f + e);
}
__device__ __forceinline__ float fast_tanh(float x) {
  x = fminf(15.0f, fmaxf(-15.0f, x));
  float e = __expf(-2.0f * x);
  return 1.0f - 2.0f * e * __builtin_amdgcn_rcpf(1.0f + e);
}

// Convert weights to f16, build W_sum = W_ih + W_hh, b_sum = b_ih + b_hh,
// stage hT as f16 into hs slot 0, zero the barrier flags.
__global__ void prep_kernel(const float* __restrict__ W_ih, const float* __restrict__ W_hh,
                            const float* __restrict__ W_fc, const float* __restrict__ b_ih,
                            const float* __restrict__ b_hh, const float* __restrict__ hT,
                            _Float16* __restrict__ w_ih_h, _Float16* __restrict__ w_sum_h,
                            _Float16* __restrict__ w_fc_h, float* __restrict__ b_sum,
                            _Float16* __restrict__ hs0, unsigned* __restrict__ flags) {
  int i0 = blockIdx.x * blockDim.x + threadIdx.x;
  int stride = gridDim.x * blockDim.x;
  for (int i = i0; i < 4096 * 1024; i += stride) {
    float a = W_ih[i];
    w_ih_h[i] = (_Float16)a;
    w_sum_h[i] = (_Float16)(a + W_hh[i]);
  }
  for (int i = i0; i < 1024 * 1024; i += stride) w_fc_h[i] = (_Float16)W_fc[i];
  for (int i = i0; i < 4096; i += stride) b_sum[i] = b_ih[i] + b_hh[i];
  for (int i = i0; i < NBATCH * Hh; i += stride) hs0[i] = (_Float16)hT[i];
  for (int i = i0; i < 256; i += stride) flags[i] = 0;
}

// Persistent LSTM kernel: 256 WGs (one per CU), 4 waves each.
// WG owns n-rows [n0, n0+32) x hidden cols [j0, j0+16) for all 4 gates.
// Wave w owns K-range [256w, 256w+256); weight fragments live in VGPRs.
// Per step: MFMA partials -> LDS cross-wave reduce -> elementwise (c in regs)
// -> h stored f16 to hs[s+1] -> group-local flag barrier (64 WGs per n-group).
__global__ __launch_bounds__(256, 1) void lstm_kernel(
    const _Float16* __restrict__ w_ih_h, const _Float16* __restrict__ w_sum_h,
    const float* __restrict__ b_sum, _Float16* __restrict__ hs,
    unsigned* __restrict__ flags) {
  const int wg = blockIdx.x;
  const int g = wg >> 6;        // n-group 0..3
  const int jb = wg & 63;       // j-block 0..63
  const int n0 = g * 32;
  const int j0 = jb * 16;
  const int tid = threadIdx.x;
  const int wave = tid >> 6;
  const int lane = tid & 63;
  const int l15 = lane & 15;
  const int quad = lane >> 4;
  const int kbase = wave * 256;
  const int own_mt = wave >> 1;        // which 16-row half this wave reduces
  const int own_r0 = (wave & 1) * 2;   // which reg pair this wave reduces

  __shared__ float part[4][2][4][4][64];  // [srcwave][mt][gate][reg][lane] = 32KB

  unsigned* gflags = flags + g * 64;

  float bias[4];
#pragma unroll
  for (int gt = 0; gt < 4; ++gt) bias[gt] = b_sum[gt * 1024 + j0 + l15];

  half8 B[4][8];              // 128 VGPRs of resident weights per wave
  float cst[2] = {0.0f, 0.0f};  // persistent cell state (this wave's slots)

  auto load_B = [&](const _Float16* w) {
#pragma unroll
    for (int gt = 0; gt < 4; ++gt) {
      const _Float16* rp = w + (size_t)(gt * 1024 + j0 + l15) * Hh + kbase + quad * 8;
#pragma unroll
      for (int ks = 0; ks < 8; ++ks) B[gt][ks] = *(const half8*)(rp + ks * 32);
    }
  };

  auto do_step = [&](const _Float16* hsrc, _Float16* hdst, int tgt, bool bar) {
    floatx4 acc[2][4] = {};
    const _Float16* a0p = hsrc + (size_t)(n0 + l15) * Hh + kbase + quad * 8;
    const _Float16* a1p = a0p + 16 * Hh;
#pragma unroll
    for (int ks = 0; ks < 8; ++ks) {
      half8 a0 = *(const half8*)(a0p + ks * 32);
      half8 a1 = *(const half8*)(a1p + ks * 32);
#pragma unroll
      for (int gt = 0; gt < 4; ++gt) {
        acc[0][gt] = __builtin_amdgcn_mfma_f32_16x16x32_f16(a0, B[gt][ks], acc[0][gt], 0, 0, 0);
        acc[1][gt] = __builtin_amdgcn_mfma_f32_16x16x32_f16(a1, B[gt][ks], acc[1][gt], 0, 0, 0);
      }
    }
#pragma unroll
    for (int mt = 0; mt < 2; ++mt)
#pragma unroll
      for (int gt = 0; gt < 4; ++gt)
#pragma unroll
        for (int r = 0; r < 4; ++r) part[wave][mt][gt][r][lane] = acc[mt][gt][r];
    __syncthreads();

    float gv[4][2];
#pragma unroll
    for (int gt = 0; gt < 4; ++gt)
#pragma unroll
      for (int rr = 0; rr < 2; ++rr) {
        float s = bias[gt];
#pragma unroll
        for (int src = 0; src < 4; ++src) s += part[src][own_mt][gt][own_r0 + rr][lane];
        gv[gt][rr] = s;
      }
#pragma unroll
    for (int rr = 0; rr < 2; ++rr) {
      float ig = fast_sigmoid(gv[0][rr]);
      float fg = fast_sigmoid(gv[1][rr]);
      float gg = fast_tanh(gv[2][rr]);
      float og = fast_sigmoid(gv[3][rr]);
      float c = fg * cst[rr] + ig * gg;
      cst[rr] = c;
      float h = og * fast_tanh(c);
      int row = n0 + own_mt * 16 + quad * 4 + own_r0 + rr;
      hdst[(size_t)row * Hh + j0 + l15] = (_Float16)h;
    }
    __syncthreads();  // protect LDS reuse next step; also drains h stores per-wave

    if (bar) {
      if (tid == 0) {
        __threadfence();  // agent-scope release: push h stores to coherence point
        __hip_atomic_store(&gflags[jb], (unsigned)tgt, __ATOMIC_RELAXED,
                           __HIP_MEMORY_SCOPE_AGENT);
      }
      if (wave == 0) {
        while (1) {
          unsigned v = __hip_atomic_load(&gflags[lane], __ATOMIC_RELAXED,
                                         __HIP_MEMORY_SCOPE_AGENT);
          if (__all((int)(v >= (unsigned)tgt))) break;
          __builtin_amdgcn_s_sleep(2);
        }
        __threadfence();  // agent-scope acquire: invalidate stale L1/L2 before h reads
      }
      __syncthreads();
    }
  };

  // Step 0: x = hT, hx = 0  =>  gates = hT @ W_ih^T + b_sum
  load_B(w_ih_h);
  do_step(hs, hs + SLOT, 1, true);
  // Steps 1..255: x = hx = h  =>  gates = h @ (W_ih+W_hh)^T + b_sum
  load_B(w_sum_h);
  for (int s = 1; s < TSTEPS; ++s) {
    do_step(hs + (size_t)s * SLOT, hs + (size_t)(s + 1) * SLOT, s + 1, s < TSTEPS - 1);
  }
}

// recons[n, s, :] = h_s @ W_fc^T + b_fc.  A = hs slots 1..256 viewed as
// [32768 x 1024] f16 (row r = s*128 + n). 64x64 tiles, 4 waves of 16 rows.
__global__ __launch_bounds__(256) void fc_kernel(const _Float16* __restrict__ A,
                                                 const _Float16* __restrict__ Bw,
                                                 const float* __restrict__ b_fc,
                                                 float* __restrict__ out) {
  const int nb = blockIdx.x;  // 0..15  (d blocks of 64)
  const int mb = blockIdx.y;  // 0..511 (row blocks of 64)
  const int tid = threadIdx.x;
  const int wave = tid >> 6;
  const int lane = tid & 63;
  const int l15 = lane & 15;
  const int quad = lane >> 4;
  const int m0 = mb * 64 + wave * 16;
  const int d0 = nb * 64;

  floatx4 acc[4] = {};
  const _Float16* ap = A + (size_t)(m0 + l15) * Hh + quad * 8;
  const _Float16* bp = Bw + (size_t)(d0 + l15) * Hh + quad * 8;
#pragma unroll 4
  for (int k = 0; k < Hh; k += 32) {
    half8 a = *(const half8*)(ap + k);
#pragma unroll
    for (int ct = 0; ct < 4; ++ct) {
      half8 b = *(const half8*)(bp + (size_t)ct * 16 * Hh + k);
      acc[ct] = __builtin_amdgcn_mfma_f32_16x16x32_f16(a, b, acc[ct], 0, 0, 0);
    }
  }
#pragma unroll
  for (int ct = 0; ct < 4; ++ct) {
    int d = d0 + ct * 16 + l15;
    float bv = b_fc[d];
#pragma unroll
    for (int r = 0; r < 4; ++r) {
      int row = m0 + quad * 4 + r;
      int s = row >> 7;
      int n = row & 127;
      out[((size_t)n * TSTEPS + s) * DOUT + d] = acc[ct][r] + bv;
    }
  }
}

extern "C" void kernel_launch(void* const* d_in, const int* in_sizes, int n_in,
                              void* d_out, int out_size, void* d_ws, size_t ws_size,
                              hipStream_t stream) {
  const float* hT   = (const float*)d_in[0];
  const float* W_ih = (const float*)d_in[1];
  const float* W_hh = (const float*)d_in[2];
  const float* b_ih = (const float*)d_in[3];
  const float* b_hh = (const float*)d_in[4];
  const float* W_fc = (const float*)d_in[5];
  const float* b_fc = (const float*)d_in[6];
  float* out = (float*)d_out;

  char* ws = (char*)d_ws;
  unsigned* flags   = (unsigned*)ws;                    // 1KB (4 groups x 64)
  float* b_sum      = (float*)(ws + 4096);              // 16KB
  _Float16* w_ih_h  = (_Float16*)(ws + 65536);          // 8MB
  _Float16* w_sum_h = w_ih_h + (size_t)4096 * 1024;     // 8MB
  _Float16* w_fc_h  = w_sum_h + (size_t)4096 * 1024;    // 2MB
  _Float16* hs      = w_fc_h + (size_t)1024 * 1024;     // 257 * 256KB = 67.3MB

  prep_kernel<<<4096, 256, 0, stream>>>(W_ih, W_hh, W_fc, b_ih, b_hh, hT,
                                        w_ih_h, w_sum_h, w_fc_h, b_sum, hs, flags);
  lstm_kernel<<<256, 256, 0, stream>>>(w_ih_h, w_sum_h, b_sum, hs, flags);
  fc_kernel<<<dim3(16, 512), 256, 0, stream>>>(hs + SLOT, w_fc_h, b_fc, out);
}

// Round 2
// 2352.275 us; speedup vs baseline: 1.8423x; 1.8423x over previous
//
#include <hip/hip_runtime.h>

#define Hh 1024
#define NBATCH 128
#define TSTEPS 256
#define DOUT 1024
#define SLOT (NBATCH * Hh)

typedef _Float16 half8 __attribute__((ext_vector_type(8)));
typedef float floatx4 __attribute__((ext_vector_type(4)));

__device__ __forceinline__ float fast_sigmoid(float x) {
  float e = __expf(-x);
  return __builtin_amdgcn_rcpf(1.0f + e);
}
__device__ __forceinline__ float fast_tanh(float x) {
  x = fminf(15.0f, fmaxf(-15.0f, x));
  float e = __expf(-2.0f * x);
  return 1.0f - 2.0f * e * __builtin_amdgcn_rcpf(1.0f + e);
}

// Convert weights to f16, build W_sum = W_ih + W_hh, b_sum = b_ih + b_hh,
// stage hT as f16 into hs slot 0, zero the barrier flags.
__global__ void prep_kernel(const float* __restrict__ W_ih, const float* __restrict__ W_hh,
                            const float* __restrict__ W_fc, const float* __restrict__ b_ih,
                            const float* __restrict__ b_hh, const float* __restrict__ hT,
                            _Float16* __restrict__ w_ih_h, _Float16* __restrict__ w_sum_h,
                            _Float16* __restrict__ w_fc_h, float* __restrict__ b_sum,
                            _Float16* __restrict__ hs0, unsigned* __restrict__ flags) {
  int i0 = blockIdx.x * blockDim.x + threadIdx.x;
  int stride = gridDim.x * blockDim.x;
  for (int i = i0; i < 4096 * 1024; i += stride) {
    float a = W_ih[i];
    w_ih_h[i] = (_Float16)a;
    w_sum_h[i] = (_Float16)(a + W_hh[i]);
  }
  for (int i = i0; i < 1024 * 1024; i += stride) w_fc_h[i] = (_Float16)W_fc[i];
  for (int i = i0; i < 4096; i += stride) b_sum[i] = b_ih[i] + b_hh[i];
  for (int i = i0; i < NBATCH * Hh; i += stride) hs0[i] = (_Float16)hT[i];
  for (int i = i0; i < 256; i += stride) flags[i] = 0;
}

// Persistent LSTM kernel: 256 WGs (one per CU), 4 waves each.
// WG owns n-rows [n0, n0+32) x hidden cols [j0, j0+16) for all 4 gates.
// Wave w owns K-range [256w, 256w+256); weight fragments live in VGPRs.
//
// Coherence scheme (fence-free): the hs ring is write-once (each address
// stored exactly once, read only after the flag barrier), so consumer
// L1/L2 can never hold stale copies of addresses they haven't touched.
// h stores are relaxed AGENT-scope atomics (sc1 -> write-through to the
// coherent point, no dirty L2, no buffer_wbl2 needed); __syncthreads()
// drains vmcnt before the flag store; flags are relaxed AGENT atomics
// (cache-bypassing) on both ends. A-tile reads are plain dwordx4 loads:
// cold lines miss to the coherent point and see current data. No
// __threadfence anywhere -> no per-step L2 writeback/invalidate storms.
__global__ __launch_bounds__(256, 1) void lstm_kernel(
    const _Float16* __restrict__ w_ih_h, const _Float16* __restrict__ w_sum_h,
    const float* __restrict__ b_sum, _Float16* __restrict__ hs,
    unsigned* __restrict__ flags) {
  const int wg = blockIdx.x;
  const int g = wg >> 6;        // n-group 0..3
  const int jb = wg & 63;       // j-block 0..63
  const int n0 = g * 32;
  const int j0 = jb * 16;
  const int tid = threadIdx.x;
  const int wave = tid >> 6;
  const int lane = tid & 63;
  const int l15 = lane & 15;
  const int quad = lane >> 4;
  const int kbase = wave * 256;
  const int own_mt = wave >> 1;        // which 16-row half this wave reduces
  const int own_r0 = (wave & 1) * 2;   // which reg pair this wave reduces

  __shared__ float part[4][2][4][4][64];  // [srcwave][mt][gate][reg][lane] = 32KB

  unsigned* gflags = flags + g * 64;

  float bias[4];
#pragma unroll
  for (int gt = 0; gt < 4; ++gt) bias[gt] = b_sum[gt * 1024 + j0 + l15];

  half8 B[4][8];              // 128 VGPRs of resident weights per wave
  float cst[2] = {0.0f, 0.0f};  // persistent cell state (this wave's slots)

  auto load_B = [&](const _Float16* w) {
#pragma unroll
    for (int gt = 0; gt < 4; ++gt) {
      const _Float16* rp = w + (size_t)(gt * 1024 + j0 + l15) * Hh + kbase + quad * 8;
#pragma unroll
      for (int ks = 0; ks < 8; ++ks) B[gt][ks] = *(const half8*)(rp + ks * 32);
    }
  };

  auto do_step = [&](const _Float16* hsrc, _Float16* hdst, int tgt, bool bar) {
    floatx4 acc[2][4] = {};
    const _Float16* a0p = hsrc + (size_t)(n0 + l15) * Hh + kbase + quad * 8;
    const _Float16* a1p = a0p + 16 * Hh;
#pragma unroll
    for (int ks = 0; ks < 8; ++ks) {
      half8 a0 = *(const half8*)(a0p + ks * 32);
      half8 a1 = *(const half8*)(a1p + ks * 32);
#pragma unroll
      for (int gt = 0; gt < 4; ++gt) {
        acc[0][gt] = __builtin_amdgcn_mfma_f32_16x16x32_f16(a0, B[gt][ks], acc[0][gt], 0, 0, 0);
        acc[1][gt] = __builtin_amdgcn_mfma_f32_16x16x32_f16(a1, B[gt][ks], acc[1][gt], 0, 0, 0);
      }
    }
#pragma unroll
    for (int mt = 0; mt < 2; ++mt)
#pragma unroll
      for (int gt = 0; gt < 4; ++gt)
#pragma unroll
        for (int r = 0; r < 4; ++r) part[wave][mt][gt][r][lane] = acc[mt][gt][r];
    __syncthreads();

    float gv[4][2];
#pragma unroll
    for (int gt = 0; gt < 4; ++gt)
#pragma unroll
      for (int rr = 0; rr < 2; ++rr) {
        float s = bias[gt];
#pragma unroll
        for (int src = 0; src < 4; ++src) s += part[src][own_mt][gt][own_r0 + rr][lane];
        gv[gt][rr] = s;
      }
#pragma unroll
    for (int rr = 0; rr < 2; ++rr) {
      float ig = fast_sigmoid(gv[0][rr]);
      float fg = fast_sigmoid(gv[1][rr]);
      float gg = fast_tanh(gv[2][rr]);
      float og = fast_sigmoid(gv[3][rr]);
      float c = fg * cst[rr] + ig * gg;
      cst[rr] = c;
      float h = og * fast_tanh(c);
      int row = n0 + own_mt * 16 + quad * 4 + own_r0 + rr;
      _Float16 hv = (_Float16)h;
      unsigned short ub;
      __builtin_memcpy(&ub, &hv, 2);
      // sc1 write-through store: visible at the coherent point once vmcnt
      // retires; no dirty L2 line left behind.
      __hip_atomic_store((unsigned short*)(hdst + (size_t)row * Hh + j0 + l15), ub,
                         __ATOMIC_RELAXED, __HIP_MEMORY_SCOPE_AGENT);
    }
    // Drains vmcnt(0) (h stores reach coherent point) + protects LDS reuse.
    __syncthreads();

    if (bar) {
      if (tid == 0) {
        __hip_atomic_store(&gflags[jb], (unsigned)tgt, __ATOMIC_RELAXED,
                           __HIP_MEMORY_SCOPE_AGENT);
      }
      if (wave == 0) {
        while (1) {
          unsigned v = __hip_atomic_load(&gflags[lane], __ATOMIC_RELAXED,
                                         __HIP_MEMORY_SCOPE_AGENT);
          if (__all((int)(v >= (unsigned)tgt))) break;
          __builtin_amdgcn_s_sleep(1);
        }
      }
      __syncthreads();
    }
  };

  // Step 0: x = hT, hx = 0  =>  gates = hT @ W_ih^T + b_sum
  load_B(w_ih_h);
  do_step(hs, hs + SLOT, 1, true);
  // Steps 1..255: x = hx = h  =>  gates = h @ (W_ih+W_hh)^T + b_sum
  load_B(w_sum_h);
  for (int s = 1; s < TSTEPS; ++s) {
    do_step(hs + (size_t)s * SLOT, hs + (size_t)(s + 1) * SLOT, s + 1, s < TSTEPS - 1);
  }
}

// recons[n, s, :] = h_s @ W_fc^T + b_fc.  A = hs slots 1..256 viewed as
// [32768 x 1024] f16 (row r = s*128 + n). 64x64 tiles, 4 waves of 16 rows.
__global__ __launch_bounds__(256) void fc_kernel(const _Float16* __restrict__ A,
                                                 const _Float16* __restrict__ Bw,
                                                 const float* __restrict__ b_fc,
                                                 float* __restrict__ out) {
  const int nb = blockIdx.x;  // 0..15  (d blocks of 64)
  const int mb = blockIdx.y;  // 0..511 (row blocks of 64)
  const int tid = threadIdx.x;
  const int wave = tid >> 6;
  const int lane = tid & 63;
  const int l15 = lane & 15;
  const int quad = lane >> 4;
  const int m0 = mb * 64 + wave * 16;
  const int d0 = nb * 64;

  floatx4 acc[4] = {};
  const _Float16* ap = A + (size_t)(m0 + l15) * Hh + quad * 8;
  const _Float16* bp = Bw + (size_t)(d0 + l15) * Hh + quad * 8;
#pragma unroll 4
  for (int k = 0; k < Hh; k += 32) {
    half8 a = *(const half8*)(ap + k);
#pragma unroll
    for (int ct = 0; ct < 4; ++ct) {
      half8 b = *(const half8*)(bp + (size_t)ct * 16 * Hh + k);
      acc[ct] = __builtin_amdgcn_mfma_f32_16x16x32_f16(a, b, acc[ct], 0, 0, 0);
    }
  }
#pragma unroll
  for (int ct = 0; ct < 4; ++ct) {
    int d = d0 + ct * 16 + l15;
    float bv = b_fc[d];
#pragma unroll
    for (int r = 0; r < 4; ++r) {
      int row = m0 + quad * 4 + r;
      int s = row >> 7;
      int n = row & 127;
      out[((size_t)n * TSTEPS + s) * DOUT + d] = acc[ct][r] + bv;
    }
  }
}

extern "C" void kernel_launch(void* const* d_in, const int* in_sizes, int n_in,
                              void* d_out, int out_size, void* d_ws, size_t ws_size,
                              hipStream_t stream) {
  const float* hT   = (const float*)d_in[0];
  const float* W_ih = (const float*)d_in[1];
  const float* W_hh = (const float*)d_in[2];
  const float* b_ih = (const float*)d_in[3];
  const float* b_hh = (const float*)d_in[4];
  const float* W_fc = (const float*)d_in[5];
  const float* b_fc = (const float*)d_in[6];
  float* out = (float*)d_out;

  char* ws = (char*)d_ws;
  unsigned* flags   = (unsigned*)ws;                    // 1KB (4 groups x 64)
  float* b_sum      = (float*)(ws + 4096);              // 16KB
  _Float16* w_ih_h  = (_Float16*)(ws + 65536);          // 8MB
  _Float16* w_sum_h = w_ih_h + (size_t)4096 * 1024;     // 8MB
  _Float16* w_fc_h  = w_sum_h + (size_t)4096 * 1024;    // 2MB
  _Float16* hs      = w_fc_h + (size_t)1024 * 1024;     // 257 * 256KB = 67.3MB

  prep_kernel<<<4096, 256, 0, stream>>>(W_ih, W_hh, W_fc, b_ih, b_hh, hT,
                                        w_ih_h, w_sum_h, w_fc_h, b_sum, hs, flags);
  lstm_kernel<<<256, 256, 0, stream>>>(w_ih_h, w_sum_h, b_sum, hs, flags);
  fc_kernel<<<dim3(16, 512), 256, 0, stream>>>(hs + SLOT, w_fc_h, b_fc, out);
}